// Round 1
// baseline (983.611 us; speedup 1.0000x reference)
//
#include <hip/hip_runtime.h>

#define N_NODES 50000
#define N_EDGES 800000
#define HID 128
#define OUTD 10
#define HOPS 4
#define NGRAPH 128
#define GBM 48

// ---------- int64-vs-int32 layout probe ----------
// If edge_index arrived as int64 (little-endian, values < 2^31), every odd
// int32 slot is a zero high-word. Genuine int32 data has random values there.
__global__ void detect_kernel(const int* __restrict__ ei, int* __restrict__ flag) {
  if (threadIdx.x == 0 && blockIdx.x == 0) {
    int all0 = 1;
    for (int i = 0; i < 64; ++i) {
      if (ei[2 * i + 1] != 0) { all0 = 0; break; }
    }
    flag[0] = all0;
  }
}

__device__ __forceinline__ int ld_idx(const int* p, int i, int is64) {
  return is64 ? p[2 * i] : p[i];
}

// ---------- degree histogram + per-graph node counts ----------
__global__ void count_kernel(const int* __restrict__ ei, const int* __restrict__ batch,
                             int* __restrict__ deg, float* __restrict__ cnt,
                             const int* __restrict__ flag) {
  int t = blockIdx.x * blockDim.x + threadIdx.x;
  int is64 = flag[0];
  if (t < N_EDGES) {
    int dst = ld_idx(ei, N_EDGES + t, is64);
    atomicAdd(&deg[dst], 1);
  } else if (t < N_EDGES + N_NODES) {
    int g = ld_idx(batch, t - N_EDGES, is64);
    atomicAdd(&cnt[g], 1.0f);
  }
}

__global__ void dinv_kernel(const int* __restrict__ deg, float* __restrict__ dinv) {
  int i = blockIdx.x * blockDim.x + threadIdx.x;
  if (i < N_NODES) dinv[i] = 1.0f / sqrtf(1.0f + (float)deg[i]);
}

// ---------- exclusive scan (single block) -> row_ptr, fill ----------
__global__ __launch_bounds__(1024) void scan_kernel(const int* __restrict__ deg,
                                                    int* __restrict__ row_ptr,
                                                    int* __restrict__ fill) {
  __shared__ int part[1024];
  int tid = threadIdx.x;
  const int CH = (N_NODES + 1023) / 1024;
  int s0 = tid * CH;
  int e0 = min(s0 + CH, N_NODES);
  int s = 0;
  for (int i = s0; i < e0; ++i) s += deg[i];
  part[tid] = s;
  __syncthreads();
  for (int off = 1; off < 1024; off <<= 1) {
    int v = (tid >= off) ? part[tid - off] : 0;
    __syncthreads();
    part[tid] += v;
    __syncthreads();
  }
  int run = (tid == 0) ? 0 : part[tid - 1];
  for (int i = s0; i < e0; ++i) {
    row_ptr[i] = run;
    fill[i] = run;
    run += deg[i];
  }
  if (e0 == N_NODES) row_ptr[N_NODES] = run;  // all qualifying threads write E
}

// ---------- CSR column fill ----------
__global__ void fill_kernel(const int* __restrict__ ei, int* __restrict__ fill,
                            int* __restrict__ col, const int* __restrict__ flag) {
  int e = blockIdx.x * blockDim.x + threadIdx.x;
  if (e < N_EDGES) {
    int is64 = flag[0];
    int dst = ld_idx(ei, N_EDGES + e, is64);
    int src = ld_idx(ei, e, is64);
    int pos = atomicAdd(&fill[dst], 1);
    col[pos] = src;
  }
}

// ---------- fp32 GEMM: C[M][128] = A[M][128] @ W[128][128] (+bias) ----------
// block: 256 threads, tile 48 rows x 64 cols, grid (ceil(M/48), 2)
__global__ __launch_bounds__(256) void gemm_kernel(const float* __restrict__ A,
                                                   const float* __restrict__ W,
                                                   const float* __restrict__ bias,
                                                   float* __restrict__ C, int M) {
  __shared__ float sA[GBM][129];   // +1 pad: conflict-free scalar reads
  __shared__ float sW[128][68];    // +4 pad, float4-aligned
  int tid = threadIdx.x;
  int row0 = blockIdx.x * GBM;
  int col0 = blockIdx.y * 64;

  // stage A: 48x128 = 1536 float4
  for (int it = 0; it < 6; ++it) {
    int f = it * 256 + tid;
    int r = f >> 5;
    int k4 = (f & 31) << 2;
    int gr = row0 + r;
    float4 v = make_float4(0.f, 0.f, 0.f, 0.f);
    if (gr < M) v = *(const float4*)(A + (size_t)gr * HID + k4);
    sA[r][k4] = v.x; sA[r][k4 + 1] = v.y; sA[r][k4 + 2] = v.z; sA[r][k4 + 3] = v.w;
  }
  // stage W half: 128x64 = 2048 float4
  for (int it = 0; it < 8; ++it) {
    int f = it * 256 + tid;
    int k = f >> 4;
    int c4 = (f & 15) << 2;
    *(float4*)&sW[k][c4] = *(const float4*)(W + k * HID + col0 + c4);
  }
  __syncthreads();

  int cg = tid & 15, rg = tid >> 4;
  int rr = rg * 3, cc = cg * 4;
  float acc[3][4];
#pragma unroll
  for (int i = 0; i < 3; ++i)
#pragma unroll
    for (int j = 0; j < 4; ++j) acc[i][j] = 0.f;

#pragma unroll 4
  for (int k = 0; k < 128; ++k) {
    float4 w = *(const float4*)&sW[k][cc];
    float a0 = sA[rr][k], a1 = sA[rr + 1][k], a2 = sA[rr + 2][k];
    acc[0][0] += a0 * w.x; acc[0][1] += a0 * w.y; acc[0][2] += a0 * w.z; acc[0][3] += a0 * w.w;
    acc[1][0] += a1 * w.x; acc[1][1] += a1 * w.y; acc[1][2] += a1 * w.z; acc[1][3] += a1 * w.w;
    acc[2][0] += a2 * w.x; acc[2][1] += a2 * w.y; acc[2][2] += a2 * w.z; acc[2][3] += a2 * w.w;
  }

  float4 bv = make_float4(0.f, 0.f, 0.f, 0.f);
  if (bias) bv = *(const float4*)(bias + col0 + cc);
#pragma unroll
  for (int i = 0; i < 3; ++i) {
    int gr = row0 + rr + i;
    if (gr < M) {
      float4 o;
      o.x = acc[i][0] + bv.x; o.y = acc[i][1] + bv.y;
      o.z = acc[i][2] + bv.z; o.w = acc[i][3] + bv.w;
      *(float4*)(C + (size_t)gr * HID + col0 + cc) = o;
    }
  }
}

// ---------- GCN aggregate (gather form): out = agg + xw*selfnorm + b ----------
// one wave per node; lane covers 2 features (float2 = coalesced 512B/row)
__global__ __launch_bounds__(256) void agg_kernel(const float* __restrict__ xw,
                                                  const int* __restrict__ row_ptr,
                                                  const int* __restrict__ col,
                                                  const float* __restrict__ dinv,
                                                  const float* __restrict__ bias,
                                                  float* __restrict__ out, int relu) {
  int wave = threadIdx.x >> 6;
  int lane = threadIdx.x & 63;
  int node = blockIdx.x * 4 + wave;
  if (node >= N_NODES) return;

  const float2* xr = (const float2*)xw;
  float di = dinv[node];
  float sn = di * di;
  float2 v = xr[(size_t)node * 64 + lane];
  float2 b = ((const float2*)bias)[lane];
  float2 acc;
  acc.x = v.x * sn + b.x;
  acc.y = v.y * sn + b.y;

  int s = row_ptr[node];
  int e = row_ptr[node + 1];
  for (int j = s; j < e; ++j) {
    int src = col[j];
    float w = dinv[src] * di;
    float2 u = xr[(size_t)src * 64 + lane];
    acc.x += u.x * w;
    acc.y += u.y * w;
  }
  if (relu) {
    acc.x = fmaxf(acc.x, 0.f);
    acc.y = fmaxf(acc.y, 0.f);
  }
  ((float2*)out)[(size_t)node * 64 + lane] = acc;
}

// ---------- classifier GEMM (128->10) + per-graph pooling ----------
__global__ __launch_bounds__(256) void pool_kernel(const float* __restrict__ h,
                                                   const float* __restrict__ Wc,
                                                   const float* __restrict__ bc,
                                                   const int* __restrict__ batch,
                                                   float* __restrict__ pool, int M,
                                                   const int* __restrict__ flag) {
  __shared__ float sW[HID * OUTD];
  __shared__ float spool[NGRAPH * OUTD];
  int tid = threadIdx.x;
  for (int i = tid; i < HID * OUTD; i += 256) sW[i] = Wc[i];
  for (int i = tid; i < NGRAPH * OUTD; i += 256) spool[i] = 0.f;
  __syncthreads();

  int row = blockIdx.x * 256 + tid;
  if (row < M) {
    int is64 = flag[0];
    float y[OUTD];
#pragma unroll
    for (int o = 0; o < OUTD; ++o) y[o] = bc[o];
    const float4* hr = (const float4*)(h + (size_t)row * HID);
    for (int k4 = 0; k4 < 32; ++k4) {
      float4 hv = hr[k4];
      int kb = k4 * 4;
#pragma unroll
      for (int o = 0; o < OUTD; ++o) {
        y[o] += hv.x * sW[(kb + 0) * OUTD + o];
        y[o] += hv.y * sW[(kb + 1) * OUTD + o];
        y[o] += hv.z * sW[(kb + 2) * OUTD + o];
        y[o] += hv.w * sW[(kb + 3) * OUTD + o];
      }
    }
    int g = ld_idx(batch, row, is64);
#pragma unroll
    for (int o = 0; o < OUTD; ++o) atomicAdd(&spool[g * OUTD + o], y[o]);
  }
  __syncthreads();
  for (int i = tid; i < NGRAPH * OUTD; i += 256) {
    float v = spool[i];
    if (v != 0.f) atomicAdd(&pool[i], v);
  }
}

__global__ void finalize_kernel(const float* __restrict__ pool,
                                const float* __restrict__ cnt,
                                float* __restrict__ out) {
  int i = blockIdx.x * blockDim.x + threadIdx.x;
  if (i < NGRAPH * OUTD) {
    float c = cnt[i / OUTD];
    out[i] = pool[i] / fmaxf(c, 1.0f);
  }
}

extern "C" void kernel_launch(void* const* d_in, const int* in_sizes, int n_in,
                              void* d_out, int out_size, void* d_ws, size_t ws_size,
                              hipStream_t stream) {
  const float* x      = (const float*)d_in[0];
  const int*   ei     = (const int*)d_in[1];
  const int*   batch  = (const int*)d_in[2];
  const float* W_in   = (const float*)d_in[3];
  const float* b_in   = (const float*)d_in[4];
  const float* W_hops = (const float*)d_in[5];
  const float* b_hops = (const float*)d_in[6];
  const float* W_cls  = (const float*)d_in[7];
  const float* b_cls  = (const float*)d_in[8];
  float* out = (float*)d_out;

  char* ws = (char*)d_ws;
  size_t off = 0;
  auto alloc = [&](size_t bytes) -> void* {
    void* p = ws + off;
    off += (bytes + 255) & ~(size_t)255;
    return p;
  };

  // zero-initialized region first (deg, cnt, pool)
  int*   deg     = (int*)alloc(N_NODES * 4);
  float* cnt     = (float*)alloc(NGRAPH * 4);
  float* pool    = (float*)alloc(NGRAPH * OUTD * 4);
  size_t zero_bytes = off;
  int*   flag    = (int*)alloc(4);
  int*   row_ptr = (int*)alloc((N_NODES + 1) * 4);
  int*   fill    = (int*)alloc(N_NODES * 4);
  float* dinv    = (float*)alloc(N_NODES * 4);
  int*   col     = (int*)alloc(N_EDGES * 4);
  float* bufA    = (float*)alloc((size_t)N_NODES * HID * 4);
  float* bufB    = (float*)alloc((size_t)N_NODES * HID * 4);
  float* bufC    = (float*)alloc((size_t)N_NODES * HID * 4);
  (void)ws_size; (void)in_sizes; (void)n_in; (void)out_size;

  hipMemsetAsync(d_ws, 0, zero_bytes, stream);
  detect_kernel<<<1, 64, 0, stream>>>(ei, flag);
  count_kernel<<<(N_EDGES + N_NODES + 255) / 256, 256, 0, stream>>>(ei, batch, deg, cnt, flag);
  dinv_kernel<<<(N_NODES + 255) / 256, 256, 0, stream>>>(deg, dinv);
  scan_kernel<<<1, 1024, 0, stream>>>(deg, row_ptr, fill);
  fill_kernel<<<(N_EDGES + 255) / 256, 256, 0, stream>>>(ei, fill, col, flag);

  dim3 ggrid((N_NODES + GBM - 1) / GBM, 2);
  // encoder: h = x @ W_in + b_in
  gemm_kernel<<<ggrid, 256, 0, stream>>>(x, W_in, b_in, bufA, N_NODES);

  float* h = bufA;
  float* other = bufC;
  for (int i = 0; i < HOPS; ++i) {
    gemm_kernel<<<ggrid, 256, 0, stream>>>(h, W_hops + (size_t)i * HID * HID, nullptr, bufB, N_NODES);
    agg_kernel<<<(N_NODES + 3) / 4, 256, 0, stream>>>(bufB, row_ptr, col, dinv,
                                                      b_hops + (size_t)i * HID, other,
                                                      (i < HOPS - 1) ? 1 : 0);
    float* t = h; h = other; other = t;
  }

  pool_kernel<<<(N_NODES + 255) / 256, 256, 0, stream>>>(h, W_cls, b_cls, batch, pool, N_NODES, flag);
  finalize_kernel<<<(NGRAPH * OUTD + 255) / 256, 256, 0, stream>>>(pool, cnt, out);
}

// Round 2
// 609.043 us; speedup vs baseline: 1.6150x; 1.6150x over previous
//
#include <hip/hip_runtime.h>

#define N_NODES 50000
#define N_EDGES 800000
#define HID 128
#define OUTD 10
#define HOPS 4
#define NGRAPH 128
#define GBM 48
#define CAP 64
#define OVF_MAX 4096

// ---------- int64-vs-int32 layout probe ----------
__global__ void detect_kernel(const int* __restrict__ ei, int* __restrict__ flag) {
  if (threadIdx.x == 0 && blockIdx.x == 0) {
    int all0 = 1;
    for (int i = 0; i < 64; ++i) {
      if (ei[2 * i + 1] != 0) { all0 = 0; break; }
    }
    flag[0] = all0;
  }
}

__device__ __forceinline__ int ld_idx(const int* p, int i, int is64) {
  return is64 ? p[2 * i] : p[i];
}

// ---------- single-pass CSR-with-capacity fill; counter doubles as degree ----------
__global__ __launch_bounds__(256) void fill_kernel(const int* __restrict__ ei,
                                                   int* __restrict__ fillcnt,
                                                   int* __restrict__ col_fixed,
                                                   int* __restrict__ ovf_cnt,
                                                   int* __restrict__ ovf,
                                                   const int* __restrict__ flag) {
  int is64 = flag[0];
  int base = blockIdx.x * 1024;
#pragma unroll
  for (int u = 0; u < 4; ++u) {
    int e = base + u * 256 + threadIdx.x;
    if (e < N_EDGES) {
      int dst = ld_idx(ei, N_EDGES + e, is64);
      int src = ld_idx(ei, e, is64);
      int pos = atomicAdd(&fillcnt[dst], 1);
      if (pos < CAP) {
        col_fixed[dst * CAP + pos] = src;
      } else {
        int o = atomicAdd(ovf_cnt, 1);
        if (o < OVF_MAX) { ovf[2 * o] = dst; ovf[2 * o + 1] = src; }
      }
    }
  }
}

__global__ void dinv_kernel(const int* __restrict__ fillcnt, float* __restrict__ dinv) {
  int i = blockIdx.x * blockDim.x + threadIdx.x;
  if (i < N_NODES) dinv[i] = 1.0f / sqrtf(1.0f + (float)fillcnt[i]);
}

// ---------- fp32 GEMM: C[M][128] = A[M][128] @ W[128][128] (+bias) ----------
__global__ __launch_bounds__(256) void gemm_kernel(const float* __restrict__ A,
                                                   const float* __restrict__ W,
                                                   const float* __restrict__ bias,
                                                   float* __restrict__ C, int M) {
  __shared__ float sA[GBM][129];
  __shared__ float sW[128][68];
  int tid = threadIdx.x;
  int row0 = blockIdx.x * GBM;
  int col0 = blockIdx.y * 64;

  for (int it = 0; it < 6; ++it) {
    int f = it * 256 + tid;
    int r = f >> 5;
    int k4 = (f & 31) << 2;
    int gr = row0 + r;
    float4 v = make_float4(0.f, 0.f, 0.f, 0.f);
    if (gr < M) v = *(const float4*)(A + (size_t)gr * HID + k4);
    sA[r][k4] = v.x; sA[r][k4 + 1] = v.y; sA[r][k4 + 2] = v.z; sA[r][k4 + 3] = v.w;
  }
  for (int it = 0; it < 8; ++it) {
    int f = it * 256 + tid;
    int k = f >> 4;
    int c4 = (f & 15) << 2;
    *(float4*)&sW[k][c4] = *(const float4*)(W + k * HID + col0 + c4);
  }
  __syncthreads();

  int cg = tid & 15, rg = tid >> 4;
  int rr = rg * 3, cc = cg * 4;
  float acc[3][4];
#pragma unroll
  for (int i = 0; i < 3; ++i)
#pragma unroll
    for (int j = 0; j < 4; ++j) acc[i][j] = 0.f;

#pragma unroll 4
  for (int k = 0; k < 128; ++k) {
    float4 w = *(const float4*)&sW[k][cc];
    float a0 = sA[rr][k], a1 = sA[rr + 1][k], a2 = sA[rr + 2][k];
    acc[0][0] += a0 * w.x; acc[0][1] += a0 * w.y; acc[0][2] += a0 * w.z; acc[0][3] += a0 * w.w;
    acc[1][0] += a1 * w.x; acc[1][1] += a1 * w.y; acc[1][2] += a1 * w.z; acc[1][3] += a1 * w.w;
    acc[2][0] += a2 * w.x; acc[2][1] += a2 * w.y; acc[2][2] += a2 * w.z; acc[2][3] += a2 * w.w;
  }

  float4 bv = make_float4(0.f, 0.f, 0.f, 0.f);
  if (bias) bv = *(const float4*)(bias + col0 + cc);
#pragma unroll
  for (int i = 0; i < 3; ++i) {
    int gr = row0 + rr + i;
    if (gr < M) {
      float4 o;
      o.x = acc[i][0] + bv.x; o.y = acc[i][1] + bv.y;
      o.z = acc[i][2] + bv.z; o.w = acc[i][3] + bv.w;
      *(float4*)(C + (size_t)gr * HID + col0 + cc) = o;
    }
  }
}

// ---------- GCN aggregate (gather): out = agg + xw*selfnorm + b ----------
// one wave per node; lane l preloads col slot l, broadcast via readlane
__global__ __launch_bounds__(256) void agg_kernel(const float* __restrict__ xw,
                                                  const int* __restrict__ fillcnt,
                                                  const int* __restrict__ col_fixed,
                                                  const float* __restrict__ dinv,
                                                  const float* __restrict__ bias,
                                                  const int* __restrict__ ovf_cnt,
                                                  const int* __restrict__ ovf,
                                                  float* __restrict__ out, int relu) {
  int wave = threadIdx.x >> 6;
  int lane = threadIdx.x & 63;
  int node = blockIdx.x * 4 + wave;
  if (node >= N_NODES) return;

  const float2* xr = (const float2*)xw;
  float di = dinv[node];
  float sn = di * di;
  float2 v = xr[(size_t)node * 64 + lane];
  float2 b = ((const float2*)bias)[lane];
  float2 acc;
  acc.x = v.x * sn + b.x;
  acc.y = v.y * sn + b.y;

  int deg = fillcnt[node];
  int m = min(deg, CAP);
  int cidx = 0;
  float cw = 0.f;
  if (lane < m) {
    cidx = col_fixed[node * CAP + lane];
    cw = dinv[cidx];
  }
  for (int j = 0; j < m; ++j) {
    int src = __builtin_amdgcn_readlane(cidx, j);
    float w = __uint_as_float((unsigned)__builtin_amdgcn_readlane((int)__float_as_uint(cw), j)) * di;
    float2 u = xr[(size_t)src * 64 + lane];
    acc.x += u.x * w;
    acc.y += u.y * w;
  }
  if (deg > CAP) {  // overflow fixup (expected never taken for this graph)
    int novf = min(*ovf_cnt, OVF_MAX);
    for (int o = 0; o < novf; ++o) {
      if (ovf[2 * o] == node) {
        int src = ovf[2 * o + 1];
        float w = dinv[src] * di;
        float2 u = xr[(size_t)src * 64 + lane];
        acc.x += u.x * w;
        acc.y += u.y * w;
      }
    }
  }
  if (relu) {
    acc.x = fmaxf(acc.x, 0.f);
    acc.y = fmaxf(acc.y, 0.f);
  }
  ((float2*)out)[(size_t)node * 64 + lane] = acc;
}

// ---------- classifier GEMM (128->10) + per-graph pooling + counts ----------
__global__ __launch_bounds__(256) void pool_kernel(const float* __restrict__ h,
                                                   const float* __restrict__ Wc,
                                                   const float* __restrict__ bc,
                                                   const int* __restrict__ batch,
                                                   float* __restrict__ pool,
                                                   float* __restrict__ cnt, int M,
                                                   const int* __restrict__ flag) {
  __shared__ float sW[HID * OUTD];
  __shared__ float spool[NGRAPH * OUTD];
  __shared__ float scount[NGRAPH];
  int tid = threadIdx.x;
  for (int i = tid; i < HID * OUTD; i += 256) sW[i] = Wc[i];
  for (int i = tid; i < NGRAPH * OUTD; i += 256) spool[i] = 0.f;
  if (tid < NGRAPH) scount[tid] = 0.f;
  __syncthreads();

  int row = blockIdx.x * 256 + tid;
  if (row < M) {
    int is64 = flag[0];
    float y[OUTD];
#pragma unroll
    for (int o = 0; o < OUTD; ++o) y[o] = bc[o];
    const float4* hr = (const float4*)(h + (size_t)row * HID);
    for (int k4 = 0; k4 < 32; ++k4) {
      float4 hv = hr[k4];
      int kb = k4 * 4;
#pragma unroll
      for (int o = 0; o < OUTD; ++o) {
        y[o] += hv.x * sW[(kb + 0) * OUTD + o];
        y[o] += hv.y * sW[(kb + 1) * OUTD + o];
        y[o] += hv.z * sW[(kb + 2) * OUTD + o];
        y[o] += hv.w * sW[(kb + 3) * OUTD + o];
      }
    }
    int g = ld_idx(batch, row, is64);
#pragma unroll
    for (int o = 0; o < OUTD; ++o) atomicAdd(&spool[g * OUTD + o], y[o]);
    atomicAdd(&scount[g], 1.0f);
  }
  __syncthreads();
  for (int i = tid; i < NGRAPH * OUTD; i += 256) {
    float v = spool[i];
    if (v != 0.f) atomicAdd(&pool[i], v);
  }
  if (tid < NGRAPH && scount[tid] != 0.f) atomicAdd(&cnt[tid], scount[tid]);
}

__global__ void finalize_kernel(const float* __restrict__ pool,
                                const float* __restrict__ cnt,
                                float* __restrict__ out) {
  int i = blockIdx.x * blockDim.x + threadIdx.x;
  if (i < NGRAPH * OUTD) {
    float c = cnt[i / OUTD];
    out[i] = pool[i] / fmaxf(c, 1.0f);
  }
}

extern "C" void kernel_launch(void* const* d_in, const int* in_sizes, int n_in,
                              void* d_out, int out_size, void* d_ws, size_t ws_size,
                              hipStream_t stream) {
  const float* x      = (const float*)d_in[0];
  const int*   ei     = (const int*)d_in[1];
  const int*   batch  = (const int*)d_in[2];
  const float* W_in   = (const float*)d_in[3];
  const float* b_in   = (const float*)d_in[4];
  const float* W_hops = (const float*)d_in[5];
  const float* b_hops = (const float*)d_in[6];
  const float* W_cls  = (const float*)d_in[7];
  const float* b_cls  = (const float*)d_in[8];
  float* out = (float*)d_out;

  char* ws = (char*)d_ws;
  size_t off = 0;
  auto alloc = [&](size_t bytes) -> void* {
    void* p = ws + off;
    off += (bytes + 255) & ~(size_t)255;
    return p;
  };

  // zero-initialized region first
  int*   fillcnt = (int*)alloc(N_NODES * 4);
  int*   ovf_cnt = (int*)alloc(4);
  float* pool    = (float*)alloc(NGRAPH * OUTD * 4);
  float* cnt     = (float*)alloc(NGRAPH * 4);
  size_t zero_bytes = off;
  int*   flag    = (int*)alloc(4);
  float* dinv    = (float*)alloc(N_NODES * 4);
  int*   ovf     = (int*)alloc(OVF_MAX * 2 * 4);
  int*   col_fixed = (int*)alloc((size_t)N_NODES * CAP * 4);
  float* bufA    = (float*)alloc((size_t)N_NODES * HID * 4);  // h
  float* bufB    = (float*)alloc((size_t)N_NODES * HID * 4);  // xw
  (void)ws_size; (void)in_sizes; (void)n_in; (void)out_size;

  hipMemsetAsync(d_ws, 0, zero_bytes, stream);
  detect_kernel<<<1, 64, 0, stream>>>(ei, flag);
  fill_kernel<<<(N_EDGES + 1023) / 1024, 256, 0, stream>>>(ei, fillcnt, col_fixed, ovf_cnt, ovf, flag);
  dinv_kernel<<<(N_NODES + 255) / 256, 256, 0, stream>>>(fillcnt, dinv);

  dim3 ggrid((N_NODES + GBM - 1) / GBM, 2);
  // encoder: h = x @ W_in + b_in  -> bufA
  gemm_kernel<<<ggrid, 256, 0, stream>>>(x, W_in, b_in, bufA, N_NODES);

  for (int i = 0; i < HOPS; ++i) {
    gemm_kernel<<<ggrid, 256, 0, stream>>>(bufA, W_hops + (size_t)i * HID * HID, nullptr, bufB, N_NODES);
    agg_kernel<<<(N_NODES + 3) / 4, 256, 0, stream>>>(bufB, fillcnt, col_fixed, dinv,
                                                      b_hops + (size_t)i * HID, ovf_cnt, ovf,
                                                      bufA, (i < HOPS - 1) ? 1 : 0);
  }

  pool_kernel<<<(N_NODES + 255) / 256, 256, 0, stream>>>(bufA, W_cls, b_cls, batch, pool, cnt, N_NODES, flag);
  finalize_kernel<<<(NGRAPH * OUTD + 255) / 256, 256, 0, stream>>>(pool, cnt, out);
}